// Round 21
// baseline (488.252 us; speedup 1.0000x reference)
//
#include <hip/hip_runtime.h>

#define T_TOK 4096
#define HDIM  1024
#define NEXP  8
#define FFDIM 4096
#define NPAIR 8192   // T_TOK * topk
#define MAXMT 72     // max total 128-row M-tiles across experts: 8192/128 + 8

typedef __attribute__((ext_vector_type(8))) short short8;
typedef __attribute__((ext_vector_type(8))) unsigned short ushort8;
typedef __attribute__((ext_vector_type(4))) unsigned short ushort4_t;
typedef __attribute__((ext_vector_type(4))) float f32x4;

__device__ __forceinline__ unsigned short f2bf(float f) {
  unsigned int u = __float_as_uint(f);
  u += 0x7fffu + ((u >> 16) & 1u);   // RNE
  return (unsigned short)(u >> 16);
}
__device__ __forceinline__ float bf2f(unsigned short u) {
  return __uint_as_float((unsigned int)u << 16);
}

// global -> LDS direct copy, 16B per lane. LDS dest is wave-uniform base;
// HW writes lane l at base + l*16. Global source address is per-lane.
__device__ __forceinline__ void gload16(const void* g, const void* l) {
  __builtin_amdgcn_global_load_lds(
      (const __attribute__((address_space(1))) unsigned int*)(unsigned long long)g,
      (__attribute__((address_space(3))) unsigned int*)(unsigned int)(unsigned long long)l,
      16, 0, 0);
}

// ---------------- transpose tile v2 (r14-verified pattern), 256 lanes, 256M x 64N ----------------
__device__ __forceinline__ void transpose_tile_256(
    const float* __restrict__ in, unsigned short* __restrict__ out,
    int M, int N, int my, int nx, unsigned short* t /* [64][264] */, int tid) {
  int r0 = my * 256, c0 = nx * 64;
  int colb = (tid & 15) * 4;
  int rowi = tid >> 4;
  int sw = (tid & 7) << 3;
#pragma unroll
  for (int i = 0; i < 16; i++) {
    int row = i * 16 + rowi;
    float4 v = *(const float4*)(in + (size_t)(r0 + row) * N + c0 + colb);
    int rs = row ^ sw;
    t[(colb + 0) * 264 + rs] = f2bf(v.x);
    t[(colb + 1) * 264 + rs] = f2bf(v.y);
    t[(colb + 2) * 264 + rs] = f2bf(v.z);
    t[(colb + 3) * 264 + rs] = f2bf(v.w);
  }
  __syncthreads();
  int m0 = (tid & 31) * 8;
  int nsub = tid >> 5;
#pragma unroll
  for (int i = 0; i < 8; i++) {
    int n = i * 8 + nsub;
    int sn = ((n >> 2) & 7) << 3;
    ushort8 v = *(const ushort8*)&t[n * 264 + (m0 ^ sn)];
    *(ushort8*)(out + (size_t)(c0 + n) * M + r0 + m0) = v;
  }
}

// ---- kernel A: router (ids 0..1023, atomic-free, vectorized) + WfcT v2 tiles ----
__global__ __launch_bounds__(256) void routerA_kernel(
    const float* __restrict__ x, const float* __restrict__ wg,
    unsigned short* __restrict__ xb,
    int* __restrict__ sel_e, float* __restrict__ sel_w,
    const float* __restrict__ Wfc, unsigned short* __restrict__ WfcT) {
  __shared__ unsigned short tbuf[64 * 264];
  int id = blockIdx.x;
  if (id >= 1024) {   // Wfc: [1024][4096] per expert -> 4 my x 64 nx = 256 tiles
    int b = id - 1024;
    int e = b >> 8, r = b & 255;
    transpose_tile_256(Wfc + (size_t)e * HDIM * FFDIM, WfcT + (size_t)e * HDIM * FFDIM,
                       HDIM, FFDIM, r >> 6, r & 63, tbuf, threadIdx.x);
    return;
  }
  int lane = threadIdx.x & 63;
  int t = id * 4 + (threadIdx.x >> 6);
  const float* xr = x + (size_t)t * HDIM;
  unsigned short* xo = xb + (size_t)t * HDIM;
  float acc[8] = {0, 0, 0, 0, 0, 0, 0, 0};
#pragma unroll
  for (int i = 0; i < 4; i++) {
    int h0 = i * 256 + lane * 4;
    float4 xv = *(const float4*)(xr + h0);
    *(ushort4_t*)(xo + h0) = (ushort4_t){f2bf(xv.x), f2bf(xv.y), f2bf(xv.z), f2bf(xv.w)};
    float xs[4] = {xv.x, xv.y, xv.z, xv.w};
#pragma unroll
    for (int k = 0; k < 4; k++) {
      const float* wr_ = wg + (size_t)(h0 + k) * 8;
      float4 w0 = *(const float4*)(wr_);
      float4 w1 = *(const float4*)(wr_ + 4);
      acc[0] += xs[k] * w0.x; acc[1] += xs[k] * w0.y; acc[2] += xs[k] * w0.z; acc[3] += xs[k] * w0.w;
      acc[4] += xs[k] * w1.x; acc[5] += xs[k] * w1.y; acc[6] += xs[k] * w1.z; acc[7] += xs[k] * w1.w;
    }
  }
#pragma unroll
  for (int off = 32; off > 0; off >>= 1) {
#pragma unroll
    for (int e = 0; e < 8; e++) acc[e] += __shfl_xor(acc[e], off, 64);
  }
  if (lane == 0) {
    int e0 = 0; float b0 = acc[0];
#pragma unroll
    for (int e = 1; e < 8; e++) if (acc[e] > b0) { b0 = acc[e]; e0 = e; }
    int e1 = -1; float b1 = -3.4e38f;
#pragma unroll
    for (int e = 0; e < 8; e++) if (e != e0 && acc[e] > b1) { b1 = acc[e]; e1 = e; }
    float q = expf(b1 - b0);                 // softmax denominator cancels in renorm
    float w0 = 1.0f / (1.0f + q);
    float w1 = q / (1.0f + q);
    sel_e[t * 2] = e0; sel_e[t * 2 + 1] = e1;
    sel_w[t * 2] = w0; sel_w[t * 2 + 1] = w1;
  }
}

// ---- count+scatter: ONE block, LDS cursors (no global atomics) ----
__global__ __launch_bounds__(1024) void count_scatter_kernel(
    const int* __restrict__ sel_e, int* __restrict__ counts,
    int* __restrict__ pair_token, int* __restrict__ pair_pos) {
  __shared__ int wtot[16][NEXP];
  __shared__ int wcur[16][NEXP];
  int tid = threadIdx.x;
  int wv = tid >> 6;
  int lane = tid & 63;
  int4 a = *(const int4*)(sel_e + tid * 8);
  int4 b = *(const int4*)(sel_e + tid * 8 + 4);
  int es[8] = {a.x, a.y, a.z, a.w, b.x, b.y, b.z, b.w};
  int c[NEXP] = {0, 0, 0, 0, 0, 0, 0, 0};
#pragma unroll
  for (int j = 0; j < 8; j++) c[es[j]]++;
#pragma unroll
  for (int off = 32; off > 0; off >>= 1)
#pragma unroll
    for (int e = 0; e < NEXP; e++) c[e] += __shfl_xor(c[e], off, 64);
  if (lane == 0)
#pragma unroll
    for (int e = 0; e < NEXP; e++) wtot[wv][e] = c[e];
  __syncthreads();
  if (tid == 0) {
    int tot[NEXP];
#pragma unroll
    for (int e = 0; e < NEXP; e++) {
      int s = 0;
      for (int w2 = 0; w2 < 16; w2++) s += wtot[w2][e];
      tot[e] = s;
    }
    int s = 0;
    for (int e = 0; e < NEXP; e++) {
      counts[e] = tot[e];
      int base = s;
      for (int w2 = 0; w2 < 16; w2++) { wcur[w2][e] = base; base += wtot[w2][e]; }
      s += tot[e];
    }
  }
  __syncthreads();
#pragma unroll
  for (int j = 0; j < 8; j++) {
    int e = es[j];
    int pos = atomicAdd(&wcur[wv][e], 1);      // LDS atomic, per-wave cursor
    int entry = tid * 8 + j;
    pair_token[pos] = entry >> 1;
    pair_pos[entry] = pos;
  }
}

// ---------------- combine: out[t] = sum_j w_j * (y0[pos_j] + y1[pos_j]) ----------------
__global__ __launch_bounds__(256) void combine_kernel(
    const unsigned short* __restrict__ y,   // [2][NPAIR][HDIM] bf16 partials
    const int* __restrict__ pair_pos, const float* __restrict__ sel_w,
    float* __restrict__ out) {
  int i = blockIdx.x * 256 + threadIdx.x;   // over T_TOK * (HDIM/8)
  int t = i >> 7;
  int c = (i & 127) * 8;
  int p0 = pair_pos[t * 2], p1 = pair_pos[t * 2 + 1];
  float w0 = sel_w[t * 2], w1 = sel_w[t * 2 + 1];
  const unsigned short* y1p = y + (size_t)NPAIR * HDIM;
  ushort8 a0 = *(const ushort8*)(y + (size_t)p0 * HDIM + c);
  ushort8 b0 = *(const ushort8*)(y1p + (size_t)p0 * HDIM + c);
  ushort8 a1 = *(const ushort8*)(y + (size_t)p1 * HDIM + c);
  ushort8 b1 = *(const ushort8*)(y1p + (size_t)p1 * HDIM + c);
  float r[8];
#pragma unroll
  for (int j = 0; j < 8; j++)
    r[j] = w0 * (bf2f(a0[j]) + bf2f(b0[j])) + w1 * (bf2f(a1[j]) + bf2f(b1[j]));
  float4 v0 = {r[0], r[1], r[2], r[3]};
  float4 v1 = {r[4], r[5], r[6], r[7]};
  float* op = out + (size_t)t * HDIM + c;
  *(float4*)op = v0;
  *(float4*)(op + 4) = v1;
}

// --- expert GEMMs: r13 A-ring + B-IN-REGISTERS (LDS-pipe fix, r21) ---
// Counter model (r20): interval ~1320cyc, LDS pipe saturated by 16 waves x 8
// ds_read_b128 (~1536cyc @85B/cyc/CU); MfmaUtil 23.5% = 310/1320. Fix: B-frags
// are wave-private -> stream them from L2 into a register double-buffer
// (4 global dwordx4/tile, coalesced 4-lanes-per-64B-line), keep only A in LDS
// (4 ds_read/tile, pressure halved). Wave pairs re-read B (+1x B traffic,
// HBM at 36% absorbs).
// vmcnt bookkeeping (merged stream, re-derived): per iter issue B(t+1)x4 then
// A-stage(t+2)x1; prologue A0 -> B0x4 -> A1. Top of iter t outstanding =
// [A(t), B(t)x4, A(t+1)] -> vmcnt(1) proves A(t)+B(t) landed, keeps A(t+1)
// flying. Last iter vmcnt(0) (r3/r4). vmcnt BEFORE barrier (r7). Compiler
// fences pin intra-iter issue order ("memory" asm orders all mem ops).
// A-ring: 3 slots x 8KB; WAR as r13 (slot t-1's reads preceded bar(t)).
// B dbuf: two named reg arrays, two-step unrolled loop (rule #20, no dynamic
// indexing). Epilogue: r16 LDS bounce (pitch 260). FUSET: WprojT tiles in tail.
template <int KD, int KSPL, int NTP, bool GATHER, bool SQRELU, bool FUSET>
__global__ __launch_bounds__(512, 4) void moe_gemm_kernel(
    const unsigned short* __restrict__ A0, const unsigned short* __restrict__ B0,
    const int* __restrict__ counts, const int* __restrict__ pair_token,
    unsigned short* __restrict__ Cout,
    const float* __restrict__ tin, unsigned short* __restrict__ tout) {
  constexpr int ND = SQRELU ? FFDIM : HDIM;
  constexpr int KLEN = KD / KSPL;
  constexpr int NTILES = KLEN / 32;
  constexpr int NBG = NTP * KSPL * MAXMT;

  __shared__ char lds[67584];   // A-ring 24KB; epilogue bounce 66.5KB; FUSET 2x33.8KB

  if (FUSET && blockIdx.x >= (unsigned)NBG) {
    // Wproj: [4096][1024] per expert -> 16 my x 16 nx = 256 tiles; 2 tiles/block
    int half = threadIdx.x >> 8;                   // 0 or 1
    int tau = (blockIdx.x - NBG) * 2 + half;
    int e = tau >> 8, r = tau & 255;
    unsigned short* tb = (unsigned short*)lds + half * (64 * 264);
    transpose_tile_256(tin + (size_t)e * FFDIM * HDIM, tout + (size_t)e * FFDIM * HDIM,
                       FFDIM, HDIM, r >> 4, r & 15, tb, threadIdx.x & 255);
    return;
  }

  // XCD-chunked bijective swizzle over the GEMM sub-domain (NBG % 8 == 0); nt fastest
  int d = blockIdx.x;
  int w = (d & 7) * (NBG >> 3) + (d >> 3);
  int nt = w % NTP;
  int rest = w / NTP;
  int ks = rest % KSPL;
  int mt = rest / KSPL;

  // ---- expert-tile search (wave-uniform) ----
  int eSel = -1, tloc = 0, segstart = 0, segcnt = 0;
  {
    int cumt = 0, acc = 0;
#pragma unroll
    for (int ee = 0; ee < NEXP; ee++) {
      int c = counts[ee];
      int ntl = (c + 127) >> 7;
      if (eSel < 0 && mt < cumt + ntl) { eSel = ee; tloc = mt - cumt; segstart = acc; segcnt = c; }
      cumt += ntl; acc += c;
    }
  }
  if (eSel < 0) return;

  if (!SQRELU) Cout += (size_t)ks * NPAIR * HDIM;   // split-K partial buffer

  const unsigned short* B = B0 + (size_t)eSel * ND * KD + (size_t)ks * KLEN;
  const unsigned short* Abase = A0 + (size_t)ks * KLEN;

  int tid = threadIdx.x;
  int lane = tid & 63;
  int wv = tid >> 6;       // 0..7
  int wr = wv >> 2;        // 0..1  (M)
  int wc = wv & 3;         // 0..3  (N)
  int g  = lane >> 4;      // 0..3
  int lr = lane & 15;

  // A staging: 1 gload16/thread covers 128 rows x 32K (64B rows, 4 chunks)
  int srow = tid >> 2;                       // 0..127
  int schunk = (tid & 3) ^ ((tid >> 3) & 3); // pre-swizzled source chunk
  const unsigned short* aP;
  {
    int idx = tloc * 128 + srow;
    if (idx >= segcnt) idx = segcnt - 1;     // clamp pad rows
    int p = segstart + idx;
    size_t rowoff;
    if (GATHER) rowoff = (size_t)pair_token[p] * KD;
    else        rowoff = (size_t)p * KD;
    aP = Abase + rowoff + schunk * 8;
  }
  // B per-lane fragment base: row = nt*256 + wc*64 + nj*16 + lr, chunk g
  const unsigned short* bGlob = B + (size_t)(nt * 256 + wc * 64 + lr) * KD + g * 8;

  const char* ldsc = lds;
  int ldsW = wv * 1024;                // wave-uniform (lane*16 added by HW)

  f32x4 acc[4][4];
#pragma unroll
  for (int i = 0; i < 4; i++)
#pragma unroll
    for (int j = 0; j < 4; j++) acc[i][j] = (f32x4){0.f, 0.f, 0.f, 0.f};

  int swz = (g ^ ((lr >> 1) & 3)) * 16;
  int abase0 = (wr * 64 + lr) * 64 + swz;            // + mi*1024

  short8 bfA[4], bfB[4];

  // prologue: A(0) -> B(0) -> A(1)  (issue order = vmcnt invariant)
  gload16(aP, ldsc + ldsW);
  aP += 32;
  asm volatile("" ::: "memory");
#pragma unroll
  for (int nj = 0; nj < 4; nj++)
    bfA[nj] = *(const short8*)(bGlob + (size_t)nj * 16 * KD);
  asm volatile("" ::: "memory");
  gload16(aP, ldsc + 8192 + ldsW);
  aP += 32;

  int rsOff = 0, rs2Off = 16384;
  auto step = [&](int t, short8 (&bcur)[4], short8 (&bnxt)[4]) {
    // top-of-iter: prove A(t) (LDS) and B(t) (regs) landed; A(t+1) stays in flight
    if (t < NTILES - 1) {
      asm volatile("s_waitcnt vmcnt(1)" ::: "memory");
    } else {
      asm volatile("s_waitcnt vmcnt(0)" ::: "memory");
    }
    __builtin_amdgcn_s_barrier();
    __builtin_amdgcn_sched_barrier(0);

    short8 af[4];
#pragma unroll
    for (int mi = 0; mi < 4; mi++)
      af[mi] = *(const short8*)(ldsc + rsOff + abase0 + mi * 1024);

    if (t + 1 < NTILES) {              // issue B(t+1) into the other reg buffer
#pragma unroll
      for (int nj = 0; nj < 4; nj++)
        bnxt[nj] = *(const short8*)(bGlob + (size_t)nj * 16 * KD + (t + 1) * 32);
    }
    asm volatile("" ::: "memory");     // pin order: B loads before A stage
    if (t + 2 < NTILES) {              // stage A(t+2) into slot of tile t-1
      gload16(aP, ldsc + rs2Off + ldsW);
      aP += 32;
    }

    __builtin_amdgcn_s_setprio(1);
#pragma unroll
    for (int mi = 0; mi < 4; mi++)
#pragma unroll
      for (int nj = 0; nj < 4; nj++)
        acc[mi][nj] = __builtin_amdgcn_mfma_f32_16x16x32_bf16(af[mi], bcur[nj], acc[mi][nj], 0, 0, 0);
    __builtin_amdgcn_s_setprio(0);

    rsOff  = (rsOff  == 16384) ? 0 : rsOff  + 8192;
    rs2Off = (rs2Off == 16384) ? 0 : rs2Off + 8192;
  };

  for (int tt = 0; tt < NTILES; tt += 2) {   // NTILES even (32 or 64)
    step(tt, bfA, bfB);
    step(tt + 1, bfB, bfA);
  }

  // ---- epilogue: LDS bounce -> coalesced ushort4 stores ----
  __syncthreads();                     // all waves done reading A-ring
  unsigned short* t2 = (unsigned short*)lds;   // [128][260]
#pragma unroll
  for (int mi = 0; mi < 4; mi++) {
#pragma unroll
    for (int q = 0; q < 4; q++) {
      int row = wr * 64 + mi * 16 + g * 4 + q;
#pragma unroll
      for (int nj = 0; nj < 4; nj++) {
        int col = wc * 64 + nj * 16 + lr;
        float v = acc[mi][nj][q];
        if (SQRELU) v = v > 0.f ? v * v : 0.f;
        t2[row * 260 + col] = f2bf(v);
      }
    }
  }
  __syncthreads();
  {
    int row = tid >> 2;                // 0..127
    int idx = tloc * 128 + row;
    if (idx < segcnt) {
      size_t base = (size_t)(segstart + idx) * ND + nt * 256;
      const unsigned short* src = t2 + row * 260;
#pragma unroll
      for (int i = 0; i < 16; i++) {
        int c = ((tid & 3) + i * 4) * 4;
        *(ushort4_t*)(Cout + base + c) = *(const ushort4_t*)(src + c);
      }
    }
  }
}

// ---------------- launch ----------------

extern "C" void kernel_launch(void* const* d_in, const int* in_sizes, int n_in,
                              void* d_out, int out_size, void* d_ws, size_t ws_size,
                              hipStream_t stream) {
  (void)in_sizes; (void)n_in; (void)out_size; (void)ws_size;
  const float* x     = (const float*)d_in[0];
  const float* Wg    = (const float*)d_in[1];
  const float* Wfc   = (const float*)d_in[2];
  const float* Wproj = (const float*)d_in[3];
  float* out = (float*)d_out;

  char* w = (char*)d_ws;
  size_t o = 0;
  auto take = [&](size_t n) { char* p = w + o; o += (n + 255) & ~(size_t)255; return p; };
  unsigned short* xb     = (unsigned short*)take((size_t)T_TOK * HDIM * 2);
  unsigned short* WfcT   = (unsigned short*)take((size_t)NEXP * FFDIM * HDIM * 2);
  unsigned short* WprojT = (unsigned short*)take((size_t)NEXP * HDIM * FFDIM * 2);
  unsigned short* h1     = (unsigned short*)take((size_t)NPAIR * FFDIM * 2);
  unsigned short* y      = (unsigned short*)take((size_t)2 * NPAIR * HDIM * 2);
  int*   sel_e      = (int*)take(T_TOK * 2 * 4);
  float* sel_w      = (float*)take(T_TOK * 2 * 4);
  int*   pair_token = (int*)take(NPAIR * 4);
  int*   pair_pos   = (int*)take(NPAIR * 4);
  int*   counts     = (int*)take(8 * 4);

  // A: router (1024 blocks, atomic-free) + Wfc transpose (2048 blocks), overlapped
  routerA_kernel<<<3072, 256, 0, stream>>>(x, Wg, xb, sel_e, sel_w, Wfc, WfcT);
  // B: single-block count + scatter via LDS cursors (no global atomics)
  count_scatter_kernel<<<1, 1024, 0, stream>>>(sel_e, counts, pair_token, pair_pos);

  // GEMM1 (1152 blocks) + Wproj transpose (1024 blocks, 2x tile_256 each) fused
  moe_gemm_kernel<HDIM, 1, FFDIM / 256, true, true, true>
      <<<(FFDIM / 256) * MAXMT + 1024, 512, 0, stream>>>(
          xb, WfcT, counts, pair_token, h1, Wproj, WprojT);
  // GEMM2: split-K=2 partials y (no atomics)
  moe_gemm_kernel<FFDIM, 2, HDIM / 256, false, false, false>
      <<<(HDIM / 256) * 2 * MAXMT, 512, 0, stream>>>(
          h1, WprojT, counts, pair_token, y, nullptr, nullptr);
  // combine: out[t] = w0*(y0[pos0]+y1[pos0]) + w1*(y0[pos1]+y1[pos1])
  combine_kernel<<<T_TOK * (HDIM / 8) / 256, 256, 0, stream>>>(y, pair_pos, sel_w, out);
}